// Round 5
// baseline (2571.566 us; speedup 1.0000x reference)
//
#include <hip/hip_runtime.h>
#include <hip/hip_bf16.h>

#define T_   32
#define B_   32
#define NIN_ 512
#define H_   1024
#define NOUT_ 256

__device__ __forceinline__ float bf2f(unsigned short u) {
  union { unsigned int i; float f; } x; x.i = ((unsigned int)u) << 16; return x.f;
}
__device__ __forceinline__ unsigned short f2bf(float f) {
  __hip_bfloat16 h = __float2bfloat16(f);
  return *reinterpret_cast<unsigned short*>(&h);
}

// ---------- dtype detect ----------
// Reads first 2048 halfwords of x as bf16. bf16 N(0,1) stays < 1e9; f32 buffers'
// mantissa halfwords decode to huge/NaN bf16 with p~0.38 each -> certain detection.
__global__ void init_detect(const unsigned short* __restrict__ x_raw, int* __restrict__ flag) {
  __shared__ int bad;
  if (threadIdx.x == 0) bad = 0;
  __syncthreads();
  int cnt = 0;
  for (int i = threadIdx.x; i < 2048; i += 256) {
    float v = bf2f(x_raw[i]);
    if (!(fabsf(v) < 1e9f)) cnt++;
  }
  if (cnt) atomicAdd(&bad, 1);
  __syncthreads();
  if (threadIdx.x == 0) flag[0] = bad ? 1 : 0;  // 1 = inputs are f32
}

// ---------- canonicalize any tensor to f32 (EXACT for both input dtypes) ----------
__global__ void convert_f32(const void* __restrict__ src, float* __restrict__ dst,
                            int n, const int* __restrict__ flag) {
  bool isf32 = flag[0] != 0;
  for (int i = blockIdx.x * 256 + threadIdx.x; i < n; i += gridDim.x * 256) {
    if (isf32) dst[i] = ((const float*)src)[i];
    else       dst[i] = bf2f(((const unsigned short*)src)[i]);
  }
}

// ---------- params -> float: [lam, eta, g[1024], b[1024]] ----------
__global__ void prep_params(const void* lam, const void* eta, const void* g, const void* b,
                            float* __restrict__ par, const int* __restrict__ flag) {
  bool isf32 = flag[0] != 0;
  int t = blockIdx.x * 256 + threadIdx.x;
  if (t == 0) {
    par[0] = isf32 ? ((const float*)lam)[0] : bf2f(((const unsigned short*)lam)[0]);
    par[1] = isf32 ? ((const float*)eta)[0] : bf2f(((const unsigned short*)eta)[0]);
  }
  if (t < H_) {
    par[2 + t]      = isf32 ? ((const float*)g)[t] : bf2f(((const unsigned short*)g)[t]);
    par[2 + H_ + t] = isf32 ? ((const float*)b)[t] : bf2f(((const unsigned short*)b)[t]);
  }
}

__global__ void zero_f32(float* __restrict__ p, int n) {
  int i = blockIdx.x * 256 + threadIdx.x;
  if (i < n) p[i] = 0.f;
}

// ---------- naive GEMM, all f32: C = act((ADDC?D:0) + act_in(A) @ W), W [K][N] ----------
template<int K, int N, int RELUA, int RELUOUT, int ADDC>
__global__ void ngemm(const float* __restrict__ A,
                      const float* __restrict__ W,
                      const float* __restrict__ D,
                      float* __restrict__ C) {
  int idx = blockIdx.x * 256 + threadIdx.x;   // m*N + j
  int m = idx / N, j = idx % N;
  const float* ar = A + (size_t)m * K;
  float a0 = 0.f, a1 = 0.f, a2 = 0.f, a3 = 0.f;
  for (int k = 0; k < K; k += 4) {
    float x0 = ar[k],     x1 = ar[k + 1], x2 = ar[k + 2], x3 = ar[k + 3];
    if (RELUA) {
      x0 = fmaxf(x0, 0.f); x1 = fmaxf(x1, 0.f);
      x2 = fmaxf(x2, 0.f); x3 = fmaxf(x3, 0.f);
    }
    a0 += x0 * W[(size_t)k * N + j];
    a1 += x1 * W[(size_t)(k + 1) * N + j];
    a2 += x2 * W[(size_t)(k + 2) * N + j];
    a3 += x3 * W[(size_t)(k + 3) * N + j];
  }
  float acc = (a0 + a1) + (a2 + a3);
  if (ADDC) acc += D[idx];
  if (RELUOUT) acc = fmaxf(acc, 0.f);
  C[idx] = acc;
}

// ---------- dots[t][b][s] = hist[t][b] . hist[s][b], one block per (b,s) ----------
__global__ void dots_k(const float* __restrict__ hist, float* __restrict__ dots, int t) {
  int b = blockIdx.x / (t + 1), s = blockIdx.x % (t + 1);
  const float* p = hist + ((size_t)t * B_ + b) * H_;
  const float* q = hist + ((size_t)s * B_ + b) * H_;
  float sum = 0.f;
  for (int i = threadIdx.x; i < H_; i += 256) sum += p[i] * q[i];
#pragma unroll
  for (int m = 1; m < 64; m <<= 1) sum += __shfl_xor(sum, m, 64);
  __shared__ float red[4];
  if ((threadIdx.x & 63) == 0) red[threadIdx.x >> 6] = sum;
  __syncthreads();
  if (threadIdx.x == 0)
    dots[((size_t)t * B_ + b) * T_ + s] = (red[0] + red[1]) + (red[2] + red[3]);
}

// ---------- hs = hist[t] @ W_h + zc_t + eta*sum_s lam^(t-s)*dots[b][s]*hist[s][b][:] ----------
__global__ void hs_k(const float* __restrict__ hist, const float* __restrict__ Wh,
                     const float* __restrict__ ZCt, const float* __restrict__ dots_t,
                     const float* __restrict__ par, float* __restrict__ hs, int t) {
  int idx = blockIdx.x * 256 + threadIdx.x;   // b*H + j
  int b = idx >> 10, j = idx & (H_ - 1);
  const float* ar = hist + ((size_t)t * B_ + b) * H_;
  float a0 = 0.f, a1 = 0.f, a2 = 0.f, a3 = 0.f;
  for (int k = 0; k < H_; k += 4) {
    a0 += ar[k]     * Wh[(size_t)k * H_ + j];
    a1 += ar[k + 1] * Wh[(size_t)(k + 1) * H_ + j];
    a2 += ar[k + 2] * Wh[(size_t)(k + 2) * H_ + j];
    a3 += ar[k + 3] * Wh[(size_t)(k + 3) * H_ + j];
  }
  float acc = ZCt[idx] + (a0 + a1) + (a2 + a3);
  float lam = par[0], eta = par[1];
  float w = eta;                              // eta * lam^(t-s), s = t..0
  for (int s = t; s >= 0; --s) {
    acc += w * dots_t[b * T_ + s] * hist[((size_t)s * B_ + b) * H_ + j];
    w *= lam;
  }
  hs[idx] = acc;
}

// ---------- batchnorm over batch (axis 0) per feature j, then relu -> h_cur ----------
__global__ void bn_k(const float* __restrict__ hs, const float* __restrict__ par,
                     float* __restrict__ h_cur) {
  int j = blockIdx.x * 256 + threadIdx.x;     // 0..1023
  float sum = 0.f;
#pragma unroll
  for (int b = 0; b < B_; b++) sum += hs[(size_t)b * H_ + j];
  float mu = sum * (1.f / B_);
  float sq = 0.f;
#pragma unroll
  for (int b = 0; b < B_; b++) {
    float d = hs[(size_t)b * H_ + j] - mu;
    sq += d * d;
  }
  float sig = sqrtf(sq * (1.f / B_));
  float gc = par[2 + j], bc = par[2 + H_ + j];
#pragma unroll
  for (int b = 0; b < B_; b++) {
    float v = gc * (hs[(size_t)b * H_ + j] - mu) / sig + bc;
    h_cur[(size_t)b * H_ + j] = fmaxf(v, 0.f);
  }
}

// ---------- final store with output dtype per flag ----------
__global__ void store_y(const float* __restrict__ y32, void* __restrict__ y_out,
                        const int* __restrict__ flag) {
  int i = blockIdx.x * 256 + threadIdx.x;     // 0..8191
  bool isf32 = flag[0] != 0;
  float v = y32[i];
  if (isf32) ((float*)y_out)[i] = v;
  else       ((unsigned short*)y_out)[i] = f2bf(v);
}

extern "C" void kernel_launch(void* const* d_in, const int* in_sizes, int n_in,
                              void* d_out, int out_size, void* d_ws, size_t ws_size,
                              hipStream_t stream) {
  const void* x_in = d_in[0];
  const void* W_i  = d_in[1];
  const void* W_z  = d_in[2];
  const void* W_c  = d_in[3];
  const void* W_h  = d_in[4];
  const void* W_ho = d_in[5];
  const void* W_o  = d_in[6];
  const void* lam  = d_in[7];
  const void* eta  = d_in[8];
  const void* g    = d_in[9];
  const void* bb   = d_in[10];

  char* wsp = (char*)d_ws;
  size_t off = 0;
  auto alloc = [&](size_t bytes) {
    void* p = wsp + off;
    off += (bytes + 255) & ~(size_t)255;
    return p;
  };
  int*   flag  = (int*)alloc(16);
  float* par   = (float*)alloc((2 + 2 * H_) * 4);
  float* X_f   = (float*)alloc((size_t)T_ * B_ * NIN_ * 4);
  float* Wi_f  = (float*)alloc((size_t)NIN_ * H_ * 4);
  float* Wz_f  = (float*)alloc((size_t)H_ * H_ * 4);
  float* Wc_f  = (float*)alloc((size_t)H_ * H_ * 4);
  float* Wh_f  = (float*)alloc((size_t)H_ * H_ * 4);
  float* Who_f = (float*)alloc((size_t)H_ * H_ * 4);
  float* Wo_f  = (float*)alloc((size_t)H_ * NOUT_ * 4);
  float* S_f   = (float*)alloc((size_t)T_ * B_ * H_ * 4);
  float* Z_f   = (float*)alloc((size_t)T_ * B_ * H_ * 4);
  float* hist  = (float*)alloc((size_t)T_ * B_ * H_ * 4);
  float* h_cur = (float*)alloc((size_t)B_ * H_ * 4);
  float* hs    = (float*)alloc((size_t)B_ * H_ * 4);
  float* dots  = (float*)alloc((size_t)T_ * B_ * T_ * 4);
  float* O_f   = (float*)alloc((size_t)B_ * H_ * 4);
  float* y32   = (float*)alloc((size_t)B_ * NOUT_ * 4);
  float* ZC    = S_f;  // S dead after Z computed; reuse S_f for ZC
  (void)ws_size; (void)in_sizes; (void)n_in; (void)out_size;

  // 1. detect dtype; canonicalize EVERYTHING to f32 (exact for bf16 or f32 inputs)
  init_detect<<<1, 256, 0, stream>>>((const unsigned short*)x_in, flag);
  convert_f32<<<256, 256, 0, stream>>>(x_in, X_f, T_ * B_ * NIN_, flag);
  convert_f32<<<256, 256, 0, stream>>>(W_i,  Wi_f,  NIN_ * H_, flag);
  convert_f32<<<256, 256, 0, stream>>>(W_z,  Wz_f,  H_ * H_, flag);
  convert_f32<<<256, 256, 0, stream>>>(W_c,  Wc_f,  H_ * H_, flag);
  convert_f32<<<256, 256, 0, stream>>>(W_h,  Wh_f,  H_ * H_, flag);
  convert_f32<<<256, 256, 0, stream>>>(W_ho, Who_f, H_ * H_, flag);
  convert_f32<<<256, 256, 0, stream>>>(W_o,  Wo_f,  H_ * NOUT_, flag);
  prep_params<<<4, 256, 0, stream>>>(lam, eta, g, bb, par, flag);

  // 2. phase A (carry-independent): S = relu(relu(X)@W_i); Z = relu(S@W_z); ZC = Z@W_c
  ngemm<NIN_, H_, 1, 1, 0><<<4096, 256, 0, stream>>>(X_f, Wi_f, nullptr, S_f);
  ngemm<H_, H_, 0, 1, 0><<<4096, 256, 0, stream>>>(S_f, Wz_f, nullptr, Z_f);
  ngemm<H_, H_, 0, 0, 0><<<4096, 256, 0, stream>>>(Z_f, Wc_f, nullptr, ZC);

  // 3. recurrence: one set of plain kernels per step (stream order = sync)
  zero_f32<<<(B_ * H_ + 255) / 256, 256, 0, stream>>>(h_cur, B_ * H_);
  for (int t = 0; t < T_; ++t) {
    const float* ZCt = ZC + (size_t)t * B_ * H_;
    float* histt = hist + (size_t)t * B_ * H_;
    // h_t = relu(zc_t + h_cur @ W_h)
    ngemm<H_, H_, 0, 1, 1><<<128, 256, 0, stream>>>(h_cur, Wh_f, ZCt, histt);
    // dots[b][s] for s<=t
    dots_k<<<B_ * (t + 1), 256, 0, stream>>>(hist, dots, t);
    // hs = h_t @ W_h + zc_t + attention
    hs_k<<<128, 256, 0, stream>>>(hist, Wh_f, ZCt, dots + (size_t)t * B_ * T_, par, hs, t);
    // batchnorm + relu -> h_cur
    bn_k<<<4, 256, 0, stream>>>(hs, par, h_cur);
  }

  // 4. readout: o = relu(h @ W_ho); y = relu(o @ W_o)
  ngemm<H_, H_, 0, 1, 0><<<128, 256, 0, stream>>>(h_cur, Who_f, nullptr, O_f);
  ngemm<H_, NOUT_, 0, 1, 0><<<32, 256, 0, stream>>>(O_f, Wo_f, nullptr, y32);
  store_y<<<32, 256, 0, stream>>>(y32, d_out, flag);
}